// Round 11
// baseline (92.271 us; speedup 1.0000x reference)
//
#include <hip/hip_runtime.h>

// Problem constants (B, N, K, P, D, F, H) = (8, 20, 2, 320, 3, 64, 64)
constexpr int B_ = 8, N_ = 20, K_ = 2, P_ = 320, D_ = 3, F_ = 64, H_ = 64;
constexpr int Q_ = K_ * P_;          // 640 rows = flattened (K,P)
constexpr float EPS_ = 1e-8f;
constexpr float LOG2E_ = 1.4426950408889634f;
constexpr int TILES_ = 10;           // 64-row tiles per (b,n)
constexpr int ROWS_  = 64;           // rows per tile; tile>=5 -> k=1 (uniform)

// NO inline asm (R3-R8 accuracy failures all contained asm v_pk_fma; R10's
// asm-free version passed). Packed fp32 here is via __builtin_elementwise_fma
// on a clang ext-vector — compiler-visible IR (llvm.fma.v2f32 ->
// v_pk_fma_f32), same per-lane fma semantics as fmaf, no scheduling opacity.
typedef float v2f __attribute__((ext_vector_type(2)));

__device__ __forceinline__ v2f mk2(float a, float b) { v2f r; r.x = a; r.y = b; return r; }

__device__ __forceinline__ v2f pfma(v2f a, v2f b, v2f c) {
#if __has_builtin(__builtin_elementwise_fma)
    return __builtin_elementwise_fma(a, b, c);
#else
    v2f r; r.x = fmaf(a.x, b.x, c.x); r.y = fmaf(a.y, b.y, c.y); return r;
#endif
}

// R10 structure (1600 blocks x 256: all CUs, ~25 waves/CU) with the q-pass
// deepened to 8 rows/thread x 32 slices (LDS b128 reads/thread 40 -> 20;
// LDS was the longest pole at ~12000 cyc/CU) and pair-SoA packed math
// (main-VALU pole 8000 -> ~4000 cyc/SIMD). Pair-SoA staging layout is the
// R2/R5-proven one: pair t: sA=(x_e,x_o,y_e,y_o), sB=(z_e,z_o,c_e,c_o).
__global__ __launch_bounds__(256) void main_kernel(
    const float* __restrict__ X,      // (B,N,K,P,D)
    const float* __restrict__ W,      // (B,N,K,P)
    const float* __restrict__ feats,  // (B,N,F)
    const float* __restrict__ mu,     // (N,K,D)
    const float* __restrict__ W1,     // (N,F,H)
    const float* __restrict__ Wx,     // (N,D,H)
    const float* __restrict__ b1,     // (N,H)
    const float* __restrict__ W2,     // (N,H)
    const float* __restrict__ bias2,  // (N,)
    const int* __restrict__ nbr,      // (N,2)
    float* __restrict__ wsPart,       // (1600,) tile sums
    float* __restrict__ out)          // (B,N,K,P) unnormalized
{
    __shared__ float4 sA[P_];            // pair t: (x_e,x_o,y_e,y_o)
    __shared__ float4 sB[P_];            // pair t: (z_e,z_o,c_e,c_o)
    __shared__ float4 aT[ROWS_];         // row: (4L*a0, 4L*a1, 4L*a2, -2L*|a|^2)
    __shared__ float4 xT[ROWS_];         // row: (x0, x1, x2, 0)
    __shared__ float4 gT[H_];            // h: (wx0, wx1, wx2, w2)
    __shared__ float  hbT[H_];           // h: hf + b1
    __shared__ float  part[ROWS_][33];   // row x slice partials (32 used)
    __shared__ float  red[4];
    __shared__ float  invW;              // 1/(sum W_neighbor + EPS)

    const int blk  = blockIdx.x;         // 0..1599
    const int bn   = blk / TILES_;
    const int tile = blk - bn * TILES_;
    const int b    = bn / N_;
    const int n    = bn - b * N_;
    const int tid  = threadIdx.x;        // 0..255
    const int wave = tid >> 6;
    const int lane = tid & 63;
    const int k    = (tile >= 5) ? 1 : 0;
    const int r0   = tile * ROWS_;       // row base in (k*320+p) flattening
    const int j    = nbr[n * 2 + k];     // component k pairs with neighbor k

    // ---- stage neighbor j's 640 points into pair-SoA ----
    const size_t nbase = ((size_t)b * N_ + j) * Q_;
    float wsum = 0.f;
    for (int i = tid; i < Q_; i += 256) {
        const float* xp = X + (nbase + i) * D_;
        const float x0 = xp[0], x1 = xp[1], x2 = xp[2];
        const float sq = x0 * x0 + x1 * x1 + x2 * x2;
        const float w  = W[nbase + i];
        const float c  = w * __builtin_amdgcn_exp2f(-2.f * LOG2E_ * sq);
        const int t = i >> 1, e = i & 1;
        float* pa = (float*)&sA[t];
        float* pb = (float*)&sB[t];
        pa[e] = x0; pa[2 + e] = x1; pb[e] = x2; pb[2 + e] = c;
        wsum += w;
    }
    {   // block-reduce neighbor weight sum
        float v = wsum;
        #pragma unroll
        for (int off = 32; off > 0; off >>= 1) v += __shfl_down(v, off, 64);
        if (lane == 0) red[wave] = v;
    }

    // ---- per-row params + gate tables (threads 0..63) ----
    if (tid < ROWS_) {
        const int gr = r0 + tid;         // flattened row of this (b,n)
        const float* xp = X + ((size_t)bn * Q_ + gr) * D_;
        const float x0 = xp[0], x1 = xp[1], x2 = xp[2];
        const float* mup = mu + (n * K_ + k) * D_;
        const float a0 = x0 - mup[0];
        const float a1 = x1 - mup[1];
        const float a2 = x2 - mup[2];
        const float ra2 = a0 * a0 + a1 * a1 + a2 * a2;
        aT[tid] = make_float4(a0 * (4.f * LOG2E_), a1 * (4.f * LOG2E_),
                              a2 * (4.f * LOG2E_), -2.f * LOG2E_ * ra2);
        xT[tid] = make_float4(x0, x1, x2, 0.f);

        // hb gemv: hf = feats[b,n] @ W1[n][:,h] + b1[n,h]
        const int h = tid;
        const float* fp  = feats + (size_t)bn * F_;
        const float* w1p = W1 + (size_t)n * F_ * H_ + h;
        float acc = 0.f;
        #pragma unroll 8
        for (int f = 0; f < F_; ++f)
            acc = fmaf(fp[f], w1p[(size_t)f * H_], acc);
        hbT[h] = acc + b1[n * H_ + h];
        const float* wxp = Wx + (size_t)n * D_ * H_ + h;
        gT[h] = make_float4(wxp[0], wxp[H_], wxp[2 * H_], W2[n * H_ + h]);
    }
    __syncthreads();

    if (tid == 0)
        invW = 1.f / (((red[0] + red[1]) + (red[2] + red[3])) + EPS_);

    // ---- q-pass: thread = (row-group g: 8 rows, slice s: 10 strided pairs) ----
    const int g = tid >> 5;              // 0..7 (rows 8g..8g+7 of the tile)
    const int s = tid & 31;              // 0..31
    float S0[8], S1[8], S2[8], RA[8];
    v2f acc[8];
    #pragma unroll
    for (int jj = 0; jj < 8; ++jj) {
        const float4 av = aT[g * 8 + jj];
        S0[jj] = av.x; S1[jj] = av.y; S2[jj] = av.z; RA[jj] = av.w;
        acc[jj] = mk2(0.f, 0.f);
    }
    #pragma unroll 2
    for (int i = 0; i < P_ / 32; ++i) {  // 10 pairs (20 q) per thread
        const int pi = i * 32 + s;
        const float4 A  = sA[pi];
        const float4 Bv = sB[pi];
        #pragma unroll
        for (int jj = 0; jj < 8; ++jj) {
            const v2f d = pfma(mk2(A.x, A.y), mk2(S0[jj], S0[jj]),
                          pfma(mk2(A.z, A.w), mk2(S1[jj], S1[jj]),
                          pfma(mk2(Bv.x, Bv.y), mk2(S2[jj], S2[jj]),
                               mk2(RA[jj], RA[jj]))));
            const v2f e = mk2(__builtin_amdgcn_exp2f(d.x),
                              __builtin_amdgcn_exp2f(d.y));
            acc[jj] = pfma(mk2(Bv.z, Bv.w), e, acc[jj]);
        }
    }
    #pragma unroll
    for (int jj = 0; jj < 8; ++jj)
        part[g * 8 + jj][s] = acc[jj].x + acc[jj].y;

    __syncthreads();

    // ---- tail (wave 0): combine slices, gate, scale, out + tile partial ----
    if (tid < ROWS_) {
        const int row = tid;
        const float* pr = part[row];
        float m0 = 0.f, m1 = 0.f, m2 = 0.f, m3 = 0.f;
        #pragma unroll
        for (int c = 0; c < 32; c += 4) {
            m0 += pr[c]; m1 += pr[c + 1]; m2 += pr[c + 2]; m3 += pr[c + 3];
        }
        const float msg = (m0 + m1) + (m2 + m3);

        const float4 xr = xT[row];
        float accg = bias2[n];
        #pragma unroll 8
        for (int h = 0; h < H_; ++h) {
            const float4 gv = gT[h];
            float t = fmaf(xr.x, gv.x, fmaf(xr.y, gv.y, fmaf(xr.z, gv.z, hbT[h])));
            t = fmaxf(t, 0.f);
            accg = fmaf(t, gv.w, accg);
        }
        const float u = 1.f / (1.f + __expf(-accg));
        const float wval = u * msg * invW;   // invW: exact linear factor

        out[(size_t)bn * Q_ + r0 + row] = wval;

        float v = wval;
        #pragma unroll
        for (int off = 32; off > 0; off >>= 1) v += __shfl_down(v, off, 64);
        if (tid == 0) wsPart[blk] = v;
    }
}

// ---------------- K2: normalize over (k,p) per (b,n) ----------------
__global__ __launch_bounds__(Q_) void norm_kernel(
    const float* __restrict__ wsPart, float* __restrict__ out)
{
    const int bn = blockIdx.x;
    const float* p = wsPart + bn * TILES_;
    float s0 = 0.f, s1 = 0.f;
    #pragma unroll
    for (int t = 0; t < TILES_ / 2; ++t) { s0 += p[2 * t]; s1 += p[2 * t + 1]; }
    const float inv = 1.f / ((s0 + s1) + EPS_);
    out[(size_t)bn * Q_ + threadIdx.x] *= inv;
}

extern "C" void kernel_launch(void* const* d_in, const int* in_sizes, int n_in,
                              void* d_out, int out_size, void* d_ws, size_t ws_size,
                              hipStream_t stream) {
    const float* X     = (const float*)d_in[0];
    const float* W     = (const float*)d_in[1];
    const float* feats = (const float*)d_in[2];
    const float* mu    = (const float*)d_in[3];
    const float* W1    = (const float*)d_in[4];
    const float* Wx    = (const float*)d_in[5];
    const float* b1    = (const float*)d_in[6];
    const float* W2    = (const float*)d_in[7];
    const float* bias2 = (const float*)d_in[8];
    const int*   nbr   = (const int*)d_in[9];
    float*       out   = (float*)d_out;
    float*       wsPart = (float*)d_ws;   // 1600 floats

    main_kernel<<<B_ * N_ * TILES_, 256, 0, stream>>>(
        X, W, feats, mu, W1, Wx, b1, W2, bias2, nbr, wsPart, out);
    norm_kernel<<<B_ * N_, Q_, 0, stream>>>(wsPart, out);
}

// Round 13
// 88.711 us; speedup vs baseline: 1.0401x; 1.0401x over previous
//
#include <hip/hip_runtime.h>

// Problem constants (B, N, K, P, D, F, H) = (8, 20, 2, 320, 3, 64, 64)
constexpr int B_ = 8, N_ = 20, K_ = 2, P_ = 320, D_ = 3, F_ = 64, H_ = 64;
constexpr int Q_ = K_ * P_;          // 640 rows = flattened (K,P)
constexpr float EPS_ = 1e-8f;
constexpr float LOG2E_ = 1.4426950408889634f;
constexpr int TILES_ = 10;           // 64-row tiles per (b,n)
constexpr int ROWS_  = 64;           // rows per tile; tile>=5 -> k=1 (uniform)

// Two-kernel structure (R10, proven 91.58us) — single-launch fusion via memory
// flags is DISQUALIFIED: harness replays the launch without re-zeroing out
// (R12 post-mortem), so no flag scheme can distinguish this-launch writes.
// This round adds only verified-correct compute changes to R10:
//  (1) float4-vectorized staging (X: 3 aligned float4 per 4 points; W: float4)
//  (2) gemv + gate parallelized across all 256 threads (R12's passing body).
// NO inline asm anywhere (R3-R8 curse).
__global__ __launch_bounds__(256) void main_kernel(
    const float* __restrict__ X,      // (B,N,K,P,D)
    const float* __restrict__ W,      // (B,N,K,P)
    const float* __restrict__ feats,  // (B,N,F)
    const float* __restrict__ mu,     // (N,K,D)
    const float* __restrict__ W1,     // (N,F,H)
    const float* __restrict__ Wx,     // (N,D,H)
    const float* __restrict__ b1,     // (N,H)
    const float* __restrict__ W2,     // (N,H)
    const float* __restrict__ bias2,  // (N,)
    const int* __restrict__ nbr,      // (N,2)
    float* __restrict__ wsPart,       // (1600,) tile sums
    float* __restrict__ out)          // (B,N,K,P) unnormalized
{
    __shared__ float4 sQ[Q_];            // neighbor point q: (x, y, z, c)
    __shared__ float4 aT[ROWS_];         // row: (4L*a0, 4L*a1, 4L*a2, -2L*|a|^2)
    __shared__ float4 xT[ROWS_];         // row: (x0, x1, x2, 0)
    __shared__ float4 gT[H_];            // h: (wx0, wx1, wx2, w2)
    __shared__ float  hbT[H_];           // h: hf + b1
    __shared__ float  gpart[H_][5];      // gemv f-segment partials (4 used)
    __shared__ float  tgate[ROWS_][5];   // gate h-segment partials (4 used)
    __shared__ float  part[ROWS_][17];   // row x slice partials (16 used)
    __shared__ float  red[4];
    __shared__ float  invW;              // 1/(sum W_neighbor + EPS)

    const int blk  = blockIdx.x;         // 0..1599
    const int bn   = blk / TILES_;
    const int tile = blk - bn * TILES_;
    const int b    = bn / N_;
    const int n    = bn - b * N_;
    const int tid  = threadIdx.x;        // 0..255
    const int wave = tid >> 6;
    const int lane = tid & 63;
    const int k    = (tile >= 5) ? 1 : 0;
    const int r0   = tile * ROWS_;       // row base in (k*320+p) flattening
    const int j    = nbr[n * 2 + k];     // component k pairs with neighbor k

    // ---- stage neighbor j's 640 points (vectorized: 4 points per thread) ----
    const size_t nbase = ((size_t)b * N_ + j) * Q_;
    float wsum = 0.f;
    if (tid < Q_ / 4) {                  // threads 0..159
        const int t = tid;
        const float4* xv = (const float4*)(X + nbase * D_);   // 16B-aligned
        const float4 f0 = xv[3 * t];
        const float4 f1 = xv[3 * t + 1];
        const float4 f2 = xv[3 * t + 2];
        const float4 w4 = ((const float4*)(W + nbase))[t];    // 16B-aligned
        // points: p0=(f0.x,f0.y,f0.z) p1=(f0.w,f1.x,f1.y)
        //         p2=(f1.z,f1.w,f2.x) p3=(f2.y,f2.z,f2.w)
        const float c0 = w4.x * __builtin_amdgcn_exp2f(-2.f * LOG2E_ *
                         (f0.x * f0.x + f0.y * f0.y + f0.z * f0.z));
        const float c1 = w4.y * __builtin_amdgcn_exp2f(-2.f * LOG2E_ *
                         (f0.w * f0.w + f1.x * f1.x + f1.y * f1.y));
        const float c2 = w4.z * __builtin_amdgcn_exp2f(-2.f * LOG2E_ *
                         (f1.z * f1.z + f1.w * f1.w + f2.x * f2.x));
        const float c3 = w4.w * __builtin_amdgcn_exp2f(-2.f * LOG2E_ *
                         (f2.y * f2.y + f2.z * f2.z + f2.w * f2.w));
        sQ[4 * t]     = make_float4(f0.x, f0.y, f0.z, c0);
        sQ[4 * t + 1] = make_float4(f0.w, f1.x, f1.y, c1);
        sQ[4 * t + 2] = make_float4(f1.z, f1.w, f2.x, c2);
        sQ[4 * t + 3] = make_float4(f2.y, f2.z, f2.w, c3);
        wsum = (w4.x + w4.y) + (w4.z + w4.w);
    }
    {   // block-reduce neighbor weight sum (zeros from tid>=160)
        float v = wsum;
        #pragma unroll
        for (int off = 32; off > 0; off >>= 1) v += __shfl_down(v, off, 64);
        if (lane == 0) red[wave] = v;
    }

    // ---- hb gemv, parallel over 256 threads: h = tid&63, f-seg = tid>>6 ----
    {
        const int h = tid & 63, seg = tid >> 6;
        const float* fp  = feats + (size_t)bn * F_;
        const float* w1p = W1 + (size_t)n * F_ * H_ + h;
        float acc = 0.f;
        #pragma unroll
        for (int f = 0; f < 16; ++f) {
            const int ff = seg * 16 + f;
            acc = fmaf(fp[ff], w1p[(size_t)ff * H_], acc);
        }
        gpart[h][seg] = acc;
    }

    // ---- per-row params + gate tables (threads 0..63) ----
    if (tid < ROWS_) {
        const int gr = r0 + tid;         // flattened row of this (b,n)
        const float* xp = X + ((size_t)bn * Q_ + gr) * D_;
        const float x0 = xp[0], x1 = xp[1], x2 = xp[2];
        const float* mup = mu + (n * K_ + k) * D_;
        const float a0 = x0 - mup[0];
        const float a1 = x1 - mup[1];
        const float a2 = x2 - mup[2];
        const float ra2 = a0 * a0 + a1 * a1 + a2 * a2;
        aT[tid] = make_float4(a0 * (4.f * LOG2E_), a1 * (4.f * LOG2E_),
                              a2 * (4.f * LOG2E_), -2.f * LOG2E_ * ra2);
        xT[tid] = make_float4(x0, x1, x2, 0.f);
        const float* wxp = Wx + (size_t)n * D_ * H_ + tid;
        gT[tid] = make_float4(wxp[0], wxp[H_], wxp[2 * H_], W2[n * H_ + tid]);
    }
    __syncthreads();

    if (tid < H_)
        hbT[tid] = ((gpart[tid][0] + gpart[tid][1]) +
                    (gpart[tid][2] + gpart[tid][3])) + b1[n * H_ + tid];
    if (tid == 0)
        invW = 1.f / (((red[0] + red[1]) + (red[2] + red[3])) + EPS_);

    // ---- q-pass (R10-verbatim): thread = (4 rows, 40 strided q) ----
    const int g = tid >> 4;              // 0..15 (rows 4g..4g+3 of the tile)
    const int s = tid & 15;              // 0..15
    float S0[4], S1[4], S2[4], RA[4], acc[4];
    #pragma unroll
    for (int jj = 0; jj < 4; ++jj) {
        const float4 av = aT[g * 4 + jj];
        S0[jj] = av.x; S1[jj] = av.y; S2[jj] = av.z; RA[jj] = av.w;
        acc[jj] = 0.f;
    }
    #pragma unroll 4
    for (int i = 0; i < Q_ / 16; ++i) {  // 40 q per thread
        const float4 Pq = sQ[i * 16 + s];
        #pragma unroll
        for (int jj = 0; jj < 4; ++jj) {
            const float d = fmaf(Pq.x, S0[jj],
                            fmaf(Pq.y, S1[jj],
                            fmaf(Pq.z, S2[jj], RA[jj])));
            acc[jj] = fmaf(Pq.w, __builtin_amdgcn_exp2f(d), acc[jj]);
        }
    }
    #pragma unroll
    for (int jj = 0; jj < 4; ++jj)
        part[g * 4 + jj][s] = acc[jj];

    __syncthreads();

    // ---- gate phase A, parallel: row = tid&63, h-seg = tid>>6 (16 h each) ----
    {
        const int row = tid & 63, seg = tid >> 6;
        const float4 xr = xT[row];
        float accg = 0.f;
        #pragma unroll
        for (int hh = 0; hh < 16; ++hh) {
            const int h = seg * 16 + hh;
            const float4 gv = gT[h];
            float t = fmaf(xr.x, gv.x, fmaf(xr.y, gv.y, fmaf(xr.z, gv.z, hbT[h])));
            t = fmaxf(t, 0.f);
            accg = fmaf(t, gv.w, accg);
        }
        tgate[row][seg] = accg;
    }
    __syncthreads();

    // ---- phase B (threads 0..63): combine, sigmoid, store + tile partial ----
    if (tid < ROWS_) {
        const int row = tid;
        const float* pr = part[row];
        const float msg =
            (((pr[0] + pr[1]) + (pr[2] + pr[3])) + ((pr[4] + pr[5]) + (pr[6] + pr[7]))) +
            (((pr[8] + pr[9]) + (pr[10] + pr[11])) + ((pr[12] + pr[13]) + (pr[14] + pr[15])));
        const float accg = bias2[n] + ((tgate[row][0] + tgate[row][1]) +
                                       (tgate[row][2] + tgate[row][3]));
        const float u = 1.f / (1.f + __expf(-accg));
        const float wval = u * msg * invW;   // invW: exact linear factor

        out[(size_t)bn * Q_ + r0 + row] = wval;

        float v = wval;
        #pragma unroll
        for (int off = 32; off > 0; off >>= 1) v += __shfl_down(v, off, 64);
        if (tid == 0) wsPart[blk] = v;
    }
}

// ---------------- K2: normalize over (k,p) per (b,n) ----------------
__global__ __launch_bounds__(Q_) void norm_kernel(
    const float* __restrict__ wsPart, float* __restrict__ out)
{
    const int bn = blockIdx.x;
    const float* p = wsPart + bn * TILES_;
    float s0 = 0.f, s1 = 0.f;
    #pragma unroll
    for (int t = 0; t < TILES_ / 2; ++t) { s0 += p[2 * t]; s1 += p[2 * t + 1]; }
    const float inv = 1.f / ((s0 + s1) + EPS_);
    out[(size_t)bn * Q_ + threadIdx.x] *= inv;
}

extern "C" void kernel_launch(void* const* d_in, const int* in_sizes, int n_in,
                              void* d_out, int out_size, void* d_ws, size_t ws_size,
                              hipStream_t stream) {
    const float* X     = (const float*)d_in[0];
    const float* W     = (const float*)d_in[1];
    const float* feats = (const float*)d_in[2];
    const float* mu    = (const float*)d_in[3];
    const float* W1    = (const float*)d_in[4];
    const float* Wx    = (const float*)d_in[5];
    const float* b1    = (const float*)d_in[6];
    const float* W2    = (const float*)d_in[7];
    const float* bias2 = (const float*)d_in[8];
    const int*   nbr   = (const int*)d_in[9];
    float*       out   = (float*)d_out;
    float*       wsPart = (float*)d_ws;   // 1600 floats

    main_kernel<<<B_ * N_ * TILES_, 256, 0, stream>>>(
        X, W, feats, mu, W1, Wx, b1, W2, bias2, nbr, wsPart, out);
    norm_kernel<<<B_ * N_, Q_, 0, stream>>>(wsPart, out);
}